// Round 1
// baseline (627.097 us; speedup 1.0000x reference)
//
#include <hip/hip_runtime.h>
#include <math.h>

#define NTOK 1024
#define DIMM 512
#define NHEAD 8
#define DHEAD 64
#define JTOT 1026      // NTOK + 2 null kv
#define JPAD 1088      // 17*64, padded row for unguarded loads
#define NT 17          // score slots per lane

// ---------------- LayerNorm ----------------
__global__ __launch_bounds__(128) void ln_kernel(const float* __restrict__ x,
                                                 const float* __restrict__ g,
                                                 const float* __restrict__ bb,
                                                 float* __restrict__ xn) {
    int row = blockIdx.x, tid = threadIdx.x;
    float4 v = ((const float4*)(x + row * DIMM))[tid];
    float s  = v.x + v.y + v.z + v.w;
    float ss = fmaf(v.x, v.x, fmaf(v.y, v.y, fmaf(v.z, v.z, v.w * v.w)));
#pragma unroll
    for (int off = 32; off; off >>= 1) {
        s  += __shfl_down(s, off);
        ss += __shfl_down(ss, off);
    }
    __shared__ float sm[4];
    if ((tid & 63) == 0) { sm[(tid >> 6) * 2] = s; sm[(tid >> 6) * 2 + 1] = ss; }
    __syncthreads();
    s = sm[0] + sm[2]; ss = sm[1] + sm[3];
    float mu   = s * (1.f / DIMM);
    float var  = ss * (1.f / DIMM) - mu * mu;
    float rstd = 1.f / sqrtf(var + 1e-5f);
    float4 gv = ((const float4*)g)[tid];
    float4 bv = ((const float4*)bb)[tid];
    float4 o;
    o.x = (v.x - mu) * rstd * gv.x + bv.x;
    o.y = (v.y - mu) * rstd * gv.y + bv.y;
    o.z = (v.z - mu) * rstd * gv.z + bv.z;
    o.w = (v.w - mu) * rstd * gv.w + bv.w;
    ((float4*)(xn + row * DIMM))[tid] = o;
}

// ---------------- null kv fill ----------------
__global__ __launch_bounds__(256) void nullkv_kernel(const float* __restrict__ nkv,
                                                     float* __restrict__ kT,
                                                     float* __restrict__ vv) {
    int tid = blockIdx.x * 256 + threadIdx.x;  // 1024 total
    if (tid >= NHEAD * 2 * DHEAD) return;
    int d = tid & 63, p = (tid >> 6) & 1, h = tid >> 7;
    float kval = nkv[((0 * NHEAD + h) * 2 + p) * DHEAD + d];
    float vval = nkv[((1 * NHEAD + h) * 2 + p) * DHEAD + d];
    kT[(h * DHEAD + d) * JPAD + p] = kval;
    vv[(h * JTOT + p) * DHEAD + d] = vval;
}

// ---------------- QKV GEMM: xn[1024][512] @ w_qkv[512][1536] ----------------
// scatters into q[h][n][d] (scaled 1/8), kT[h][d][2+n], v[h][2+n][d]
__global__ __launch_bounds__(256) void qkv_gemm(const float* __restrict__ A,
                                                const float* __restrict__ B,
                                                float* __restrict__ qo,
                                                float* __restrict__ kT,
                                                float* __restrict__ vo) {
    const int K = 512, Nn = 1536;
    __shared__ float As[16][64];
    __shared__ float Bs[16][64];
    int tid = threadIdx.x;
    int m0 = blockIdx.x * 64, n0 = blockIdx.y * 64;
    int ty = tid >> 4, tx = tid & 15;
    int lam = tid >> 2, lak = (tid & 3) << 2;
    int lbk = tid >> 4, lbn = (tid & 15) << 2;
    float acc[4][4] = {};
    for (int k0 = 0; k0 < K; k0 += 16) {
        float4 av = *(const float4*)(A + (m0 + lam) * K + k0 + lak);
        float4 bv = *(const float4*)(B + (size_t)(k0 + lbk) * Nn + n0 + lbn);
        As[lak + 0][lam] = av.x; As[lak + 1][lam] = av.y;
        As[lak + 2][lam] = av.z; As[lak + 3][lam] = av.w;
        *(float4*)&Bs[lbk][lbn] = bv;
        __syncthreads();
#pragma unroll
        for (int kk = 0; kk < 16; ++kk) {
            float a4[4], b4[4];
#pragma unroll
            for (int u = 0; u < 4; ++u) a4[u] = As[kk][ty * 4 + u];
#pragma unroll
            for (int u = 0; u < 4; ++u) b4[u] = Bs[kk][tx * 4 + u];
#pragma unroll
            for (int ii = 0; ii < 4; ++ii)
#pragma unroll
                for (int jj = 0; jj < 4; ++jj)
                    acc[ii][jj] = fmaf(a4[ii], b4[jj], acc[ii][jj]);
        }
        __syncthreads();
    }
#pragma unroll
    for (int ii = 0; ii < 4; ++ii) {
        int m = m0 + ty * 4 + ii;
#pragma unroll
        for (int jj = 0; jj < 4; ++jj) {
            int c = n0 + tx * 4 + jj;
            float val = acc[ii][jj];
            if (c < 512) {
                int h = c >> 6, d = c & 63;
                qo[((h << 10) + m) * 64 + d] = val * 0.125f;
            } else if (c < 1024) {
                int c2 = c - 512, h = c2 >> 6, d = c2 & 63;
                kT[(h * 64 + d) * JPAD + 2 + m] = val;
            } else {
                int c2 = c - 1024, h = c2 >> 6, d = c2 & 63;
                vo[(h * JTOT + 2 + m) * DHEAD + d] = val;
            }
        }
    }
}

// ---------------- fused sim + coordinate descent + PV ----------------
// one wave per (head,row). q pre-scaled. kT padded rows (JPAD).
__global__ __launch_bounds__(256) void cd_kernel(const float* __restrict__ q,
                                                 const float* __restrict__ kT,
                                                 const float* __restrict__ vv,
                                                 float* __restrict__ ao) {
    int wave = threadIdx.x >> 6, lane = threadIdx.x & 63;
    int r = (blockIdx.x << 2) + wave;
    int h = r >> 10, i = r & 1023;
    int nvalid = i + 3;                // null kv (2) + causal i+1
    int tmax = (nvalid + 63) >> 6;

    __shared__ float qs[4][64];
    __shared__ float ps[4][JPAD];

    qs[wave][lane] = q[((h << 10) + i) * 64 + lane];
    __syncthreads();

    // ---- scores s_j = q_i . k_j (lane owns j = lane + 64*t) ----
    float s[NT];
    const float* ktb = kT + (h << 6) * JPAD + lane;
#pragma unroll
    for (int t = 0; t < NT; ++t) {
        if (t < tmax) {
            const float* p0 = ktb + (t << 6);
            float a0 = 0.f, a1 = 0.f, a2 = 0.f, a3 = 0.f;
#pragma unroll
            for (int d = 0; d < 64; d += 4) {
                a0 = fmaf(qs[wave][d],     p0[(d) * JPAD],     a0);
                a1 = fmaf(qs[wave][d + 1], p0[(d + 1) * JPAD], a1);
                a2 = fmaf(qs[wave][d + 2], p0[(d + 2) * JPAD], a2);
                a3 = fmaf(qs[wave][d + 3], p0[(d + 3) * JPAD], a3);
            }
            s[t] = (a0 + a1) + (a2 + a3);
        }
    }
#pragma unroll
    for (int t = 0; t < NT; ++t) {
        int j = lane + (t << 6);
        if (j >= nvalid) s[t] = -3.0e38f;   // masked
    }

    // ---- coordinate descent: a is the only per-row state ----
    const float inv_eps = 10.f;
    const float logk = 2.0794415416798357f;  // ln 8
    // iteration 1 analytic: sb == 0 on mask -> lse = log(nvalid)
    float a = 0.1f * (logk - __logf((float)nvalid));
#pragma unroll 1
    for (int it = 1; it < 50; ++it) {
        float m = -__builtin_inff();
        float z[NT];
#pragma unroll
        for (int t = 0; t < NT; ++t) {
            float tmp = s[t] + a;
            float zz = (s[t] + fminf(0.f, tmp)) * inv_eps;  // masked -> -inf
            z[t] = zz;
            m = fmaxf(m, zz);
        }
#pragma unroll
        for (int off = 32; off; off >>= 1) m = fmaxf(m, __shfl_xor(m, off));
        float sum = 0.f;
#pragma unroll
        for (int t = 0; t < NT; ++t) sum += __expf(z[t] - m);
#pragma unroll
        for (int off = 32; off; off >>= 1) sum += __shfl_xor(sum, off);
        a = 0.1f * (logk - (m + __logf(sum)));
    }

    // ---- final scores -> LDS ----
#pragma unroll
    for (int t = 0; t < NT; ++t) {
        int j = lane + (t << 6);
        float tmp = s[t] + a;
        float p = __expf((tmp + fminf(0.f, tmp)) * inv_eps);
        ps[wave][j] = (j < nvalid) ? p : 0.f;
    }
    __syncthreads();

    // ---- PV: lane = d, loop j ----
    const float* vb = vv + (size_t)h * JTOT * DHEAD + lane;
    float b0 = 0.f, b1 = 0.f, b2 = 0.f, b3 = 0.f;
    int j = 0;
    for (; j + 4 <= nvalid; j += 4) {
        b0 = fmaf(ps[wave][j],     vb[(j) * 64],     b0);
        b1 = fmaf(ps[wave][j + 1], vb[(j + 1) * 64], b1);
        b2 = fmaf(ps[wave][j + 2], vb[(j + 2) * 64], b2);
        b3 = fmaf(ps[wave][j + 3], vb[(j + 3) * 64], b3);
    }
    for (; j < nvalid; ++j) b0 = fmaf(ps[wave][j], vb[j * 64], b0);
    ao[(i << 9) + (h << 6) + lane] = (b0 + b1) + (b2 + b3);
}

// ---------------- out GEMM: ao[1024][512] @ w_out[512][512] -> d_out ----------------
__global__ __launch_bounds__(256) void out_gemm(const float* __restrict__ A,
                                                const float* __restrict__ B,
                                                float* __restrict__ C) {
    const int K = 512, Nn = 512;
    __shared__ float As[16][64];
    __shared__ float Bs[16][64];
    int tid = threadIdx.x;
    int m0 = blockIdx.x * 64, n0 = blockIdx.y * 64;
    int ty = tid >> 4, tx = tid & 15;
    int lam = tid >> 2, lak = (tid & 3) << 2;
    int lbk = tid >> 4, lbn = (tid & 15) << 2;
    float acc[4][4] = {};
    for (int k0 = 0; k0 < K; k0 += 16) {
        float4 av = *(const float4*)(A + (m0 + lam) * K + k0 + lak);
        float4 bv = *(const float4*)(B + (size_t)(k0 + lbk) * Nn + n0 + lbn);
        As[lak + 0][lam] = av.x; As[lak + 1][lam] = av.y;
        As[lak + 2][lam] = av.z; As[lak + 3][lam] = av.w;
        *(float4*)&Bs[lbk][lbn] = bv;
        __syncthreads();
#pragma unroll
        for (int kk = 0; kk < 16; ++kk) {
            float a4[4], b4[4];
#pragma unroll
            for (int u = 0; u < 4; ++u) a4[u] = As[kk][ty * 4 + u];
#pragma unroll
            for (int u = 0; u < 4; ++u) b4[u] = Bs[kk][tx * 4 + u];
#pragma unroll
            for (int ii = 0; ii < 4; ++ii)
#pragma unroll
                for (int jj = 0; jj < 4; ++jj)
                    acc[ii][jj] = fmaf(a4[ii], b4[jj], acc[ii][jj]);
        }
        __syncthreads();
    }
#pragma unroll
    for (int ii = 0; ii < 4; ++ii) {
        int m = m0 + ty * 4 + ii;
#pragma unroll
        for (int jj = 0; jj < 4; ++jj) {
            int c = n0 + tx * 4 + jj;
            C[m * Nn + c] = acc[ii][jj];
        }
    }
}

extern "C" void kernel_launch(void* const* d_in, const int* in_sizes, int n_in,
                              void* d_out, int out_size, void* d_ws, size_t ws_size,
                              hipStream_t stream) {
    const float* x      = (const float*)d_in[0];
    const float* w_qkv  = (const float*)d_in[1];
    const float* w_out  = (const float*)d_in[2];
    const float* nullkv = (const float*)d_in[3];
    const float* ln_g   = (const float*)d_in[4];
    const float* ln_b   = (const float*)d_in[5];
    float* ws = (float*)d_ws;

    float* xn = ws;                                  // 1024*512
    float* q  = xn + 1024 * 512;                     // 8*1024*64
    float* kT = q + 8 * 1024 * 64;                   // 8*64*JPAD
    float* vv = kT + 8 * 64 * JPAD;                  // 8*JTOT*64
    float* ao = vv + 8 * JTOT * 64;                  // 1024*512
    float* out = (float*)d_out;

    hipLaunchKernelGGL(ln_kernel, dim3(1024), dim3(128), 0, stream, x, ln_g, ln_b, xn);
    hipLaunchKernelGGL(nullkv_kernel, dim3(4), dim3(256), 0, stream, nullkv, kT, vv);
    hipLaunchKernelGGL(qkv_gemm, dim3(16, 24), dim3(256), 0, stream, xn, w_qkv, q, kT, vv);
    hipLaunchKernelGGL(cd_kernel, dim3(2048), dim3(256), 0, stream, q, kT, vv, ao);
    hipLaunchKernelGGL(out_gemm, dim3(16, 8), dim3(256), 0, stream, ao, w_out, out);
}